// Round 6
// baseline (320.492 us; speedup 1.0000x reference)
//
#include <hip/hip_runtime.h>
#include <hip/hip_bf16.h>

// N=4096, K=48, P=128, A=5, NBINS=16, RP=32
#define N_RES 4096
#define KNB   48
#define PCH   128
#define INV_STEP 0.727272727272727f
#define E2C   7.38905609893065f       // e^2
#define EM2C  0.1353352832366127f     // e^-2
#define EM6C  2.4787521766663585e-3f  // e^-6
#define EM8C  3.3546262790251185e-4f  // e^-8

typedef __bf16 bf16x8 __attribute__((ext_vector_type(8)));
typedef float  f32x4  __attribute__((ext_vector_type(4)));
typedef float  f32x2  __attribute__((ext_vector_type(2)));   // lowers to v_pk_*_f32

// Frag-linear, PADDED layout: octet stride = 49 row-slots (16B each).
#define FOCT(o,m) (((o)*49 + (m))*8)

// wcat K-map (480 total, 60 octs):
//   0..15   dmap RBF            (octs 0..1)
//  16..415  dist RBF (25 pairs) (octs 2..51)
// 416..455  dir/vec per atom a: k=416+8a+[dx,dy,dz,vx,vy,vz,0,0] (octs 52..56)
// 456..464  rot (9)             (oct 57 + oct 58 slot 0)
// 465..479  zero                (rest of oct 58, oct 59)
__device__ __align__(16) unsigned short g_wcat[60*128*8];
// w1: K=128 (rows sigma-permuted: pairs (u,u+16) interleaved), 256 cols
__device__ __align__(16) unsigned short g_w1[16*256*8];
// w2: K=256 (rows sigma-permuted within each 128-half), 128 cols
__device__ __align__(16) unsigned short g_w2[32*128*8];

__device__ __forceinline__ unsigned short f2bf(float f) {
  unsigned int u = __float_as_uint(f);
  return (unsigned short)((u + 0x7fffu + ((u >> 16) & 1u)) >> 16);
}
__device__ __forceinline__ unsigned int pk2(float a, float b) {
  __hip_bfloat162 h = __float22bfloat162_rn(make_float2(a, b));
  unsigned int u; __builtin_memcpy(&u, &h, 4); return u;
}
// tanh-gelu == x * sigmoid(2u), u = 0.7978845608*(x + 0.044715 x^3); packed pair.
__device__ __forceinline__ f32x2 gelu2(f32x2 X) {
  f32x2 p = X*X;
  f32x2 q = p*0.044715f + 1.0f;
  f32x2 r = X*q;
  f32x2 m = r * -1.5957691216057308f;
  f32x2 E; E[0] = __expf(m[0]); E[1] = __expf(m[1]);
  f32x2 den = E + 1.0f;
  f32x2 sig; sig[0] = __builtin_amdgcn_rcpf(den[0]);
  sig[1] = __builtin_amdgcn_rcpf(den[1]);
  return X*sig;
}
__device__ __forceinline__ void frame_from_pos(const float* p, float* R) {
  float cax = p[3], cay = p[4], caz = p[5];
  float e1x = p[6]-cax, e1y = p[7]-cay, e1z = p[8]-caz;
  float i1 = __builtin_amdgcn_rsqf(fmaxf(e1x*e1x + e1y*e1y + e1z*e1z, 1e-6f));
  e1x *= i1; e1y *= i1; e1z *= i1;
  float vx = p[0]-cax, vy = p[1]-cay, vz = p[2]-caz;
  float dp = vx*e1x + vy*e1y + vz*e1z;
  float e2x = vx - dp*e1x, e2y = vy - dp*e1y, e2z = vz - dp*e1z;
  float i2 = __builtin_amdgcn_rsqf(fmaxf(e2x*e2x + e2y*e2y + e2z*e2z, 1e-6f));
  e2x *= i2; e2y *= i2; e2z *= i2;
  float e3x = e1y*e2z - e1z*e2y;
  float e3y = e1z*e2x - e1x*e2z;
  float e3z = e1x*e2y - e1y*e2x;
  R[0]=e1x; R[1]=e2x; R[2]=e3x;
  R[3]=e1y; R[4]=e2y; R[5]=e3y;
  R[6]=e1z; R[7]=e2z; R[8]=e3z;
}

// 16 RBF bins exp(-(x-b)^2) via PAIRED telescoping recurrences (up + down,
// merged with pk_max). COMPUTE-EARLY (regs) / STORE-LATE (commit) split so the
// bins VALU work for stage st+1 interleaves with the MFMA phase of stage st.
struct BinsReg { uint4 lo, hi; int base; };

__device__ __forceinline__ void bins_compute(const float* s_xall, int xbase, int i,
                                             BinsReg& br) {
  int rloc = i / 48;
  int m = i - 48*rloc;
  float x  = fminf(s_xall[(xbase + rloc)*48 + m], 23.0f);
  float u0 = __expf(-x*x);                 // bin 0
  float tt = __expf(2.0f*x - 3.0f);
  float xm = x - 15.0f;
  float d0 = __expf(-xm*xm);               // bin 15
  float ss = __expf(-2.0f*x + 29.0f);
  float t2 = tt*tt;                        // e^{4x-6}
  float s2 = ss*ss;                        // e^{-4x+58}
  f32x2 P;  P[0] = u0;       P[1] = u0*tt*E2C;        // (bin0, bin1)
  f32x2 W;  W[0] = t2*E2C;   W[1] = t2*EM2C;          // (e^{4x-4}, e^{4x-8})
  f32x2 Pn[8];
  Pn[0] = P;
  #pragma unroll
  for (int b = 1; b < 8; ++b) { P *= W; W *= EM8C; Pn[b] = P; }
  f32x2 q;  q[0] = d0*ss;    q[1] = d0;               // (bin14, bin15)
  f32x2 V;  V[0] = s2*EM6C;  V[1] = s2*EM2C;          // (e^{-4x+52}, e^{-4x+56})
  unsigned int pks[8];
  f32x2 o7 = __builtin_elementwise_max(Pn[7], q);
  pks[7] = pk2(o7[0], o7[1]);
  #pragma unroll
  for (int b = 6; b >= 0; --b) {
    q *= V; V *= EM8C;
    f32x2 o = __builtin_elementwise_max(Pn[b], q);
    pks[b] = pk2(o[0], o[1]);
  }
  br.lo = make_uint4(pks[0],pks[1],pks[2],pks[3]);
  br.hi = make_uint4(pks[4],pks[5],pks[6],pks[7]);
  br.base = FOCT(2*rloc, m);
}
__device__ __forceinline__ void bins_commit(unsigned short* sF, const BinsReg& br) {
  *(uint4*)(sF + br.base)       = br.lo;
  *(uint4*)(sF + br.base + 392) = br.hi;   // oct+1 => +49*8
}

// ---- prep: fragment-linear bf16 weights; wcat K-map per header comment;
// W1/W2 rows sigma-permuted to match paired (pk2/b32) LDS staging. ----
__global__ __launch_bounds__(256) void prep_weights(
    const float* __restrict__ W_dmap, const float* __restrict__ W_dist,
    const float* __restrict__ W_dir, const float* __restrict__ W_rot,
    const float* __restrict__ W_vec, const float* __restrict__ W1,
    const float* __restrict__ W2)
{
  int i = blockIdx.x*256 + threadIdx.x;
  unsigned short pk[8];
  if (i < 7680) {                       // wcat: oct = i>>7 (60), col = i&127
    int oct = i >> 7, col = i & 127;
    #pragma unroll
    for (int j = 0; j < 8; ++j) {
      int k = oct*8 + j;
      float v;
      if      (k < 16)  v = W_dmap[k*128 + col];
      else if (k < 416) v = W_dist[(k-16)*128 + col];
      else if (k < 456) {
        int a = (k-416) >> 3, jj = (k-416) & 7;
        v = (jj < 3) ? W_dir[(a*3+jj)*128 + col]
          : (jj < 6) ? W_vec[(a*3+jj-3)*128 + col] : 0.0f;
      }
      else if (k < 465) v = W_rot[(k-456)*128 + col];
      else              v = 0.0f;
      pk[j] = f2bf(v);
    }
    *(uint4*)(g_wcat + i*8) = *(uint4*)pk;
  } else if (i < 11776) {               // w1: oct(16) x col(256), rows permuted
    int j2 = i - 7680;
    int oct = j2 >> 8, col = j2 & 255;
    #pragma unroll
    for (int j = 0; j < 8; ++j) {
      int k = oct*8 + j;                // permuted row index
      int h = 32*(k>>5) + (k&1)*16 + ((k&31)>>1);   // original row
      pk[j] = f2bf(W1[h*256 + col]);
    }
    *(uint4*)(g_w1 + j2*8) = *(uint4*)pk;
  } else if (i < 15872) {               // w2: oct(32) x col(128), rows permuted per half
    int j3 = i - 11776;
    int oct = j3 >> 7, col = j3 & 127;
    #pragma unroll
    for (int j = 0; j < 8; ++j) {
      int k = oct*8 + j;                // permuted row 0..255
      int kh = k & 127;
      int h = (k>>7)*128 + 32*(kh>>5) + (kh&1)*16 + ((kh&31)>>1);
      pk[j] = f2bf(W2[h*128 + col]);
    }
    *(uint4*)(g_w2 + j3*8) = *(uint4*)pk;
  }
}

#define MFMA6(A0,A1,A2,B0,B1,ACC) \
  ACC[0][0] = __builtin_amdgcn_mfma_f32_16x16x32_bf16(A0, B0, ACC[0][0], 0,0,0); \
  ACC[1][0] = __builtin_amdgcn_mfma_f32_16x16x32_bf16(A1, B0, ACC[1][0], 0,0,0); \
  ACC[2][0] = __builtin_amdgcn_mfma_f32_16x16x32_bf16(A2, B0, ACC[2][0], 0,0,0); \
  ACC[0][1] = __builtin_amdgcn_mfma_f32_16x16x32_bf16(A0, B1, ACC[0][1], 0,0,0); \
  ACC[1][1] = __builtin_amdgcn_mfma_f32_16x16x32_bf16(A1, B1, ACC[1][1], 0,0,0); \
  ACC[2][1] = __builtin_amdgcn_mfma_f32_16x16x32_bf16(A2, B1, ACC[2][1], 0,0,0);

// ---- main: one block per residue, 256 threads; LDS 25600 B -> 6 blocks/CU ----
__global__ __launch_bounds__(256, 6) void fused_struct_kernel(
    const float* __restrict__ pos, const float* __restrict__ dmap,
    const float* __restrict__ mask, const float* __restrict__ W_relpos,
    const float* __restrict__ ln_scale, const float* __restrict__ ln_offset,
    const float* __restrict__ b1, const float* __restrict__ b2,
    const int* __restrict__ neighbours, const int* __restrict__ resi,
    const int* __restrict__ chain, const int* __restrict__ batch,
    float* __restrict__ out)
{
  const int n = blockIdx.x;
  const int t = threadIdx.x;
  const int lane = t & 63;
  const int wv   = t >> 6;
  const int ln15 = lane & 15;
  const int quad = lane >> 4;

  __shared__ __align__(16) char regF[12544];   // F stage / gelu half0 (padded frag-linear)
  __shared__ __align__(16) char regP[12672];   // scratch -> pairb -> gelu half1
  __shared__ __align__(16) float2 s_stats[48];

  unsigned short* sF    = (unsigned short*)regF;
  unsigned short* sPair = (unsigned short*)regP;
  // Conflict-free strides: 17 and 13 floats (gcd with 32 banks == 1).
  float*  s_posnb = (float*)regP;              // [48][17]  = 3264 B
  float*  s_Rnb   = (float*)(regP + 3264);     // [48][13]  = 2496 B
  float*  s_xall  = (float*)(regP + 5760);     // [26][48]  = 4992 B
  float*  s_posn  = (float*)(regP + 10752);    // 64 B
  float*  s_Rn    = (float*)(regP + 10816);    // 64 B
  int*    s_cls   = (int*)  (regP + 10880);    // 192 B
  float2* s_part  = (float2*)(regP + 11072);   // [4][48] = 1536 B, ends 12608 <= 12672

  // ---------------- P1 ----------------
  if (t < KNB) {
    const int k = t;
    const int nbraw = neighbours[n*KNB + k];
    int nb = nbraw; if (nb < 0) nb += N_RES;
    float p[15];
    const float* pp = pos + nb*15;
    #pragma unroll
    for (int d = 0; d < 15; ++d) { p[d] = pp[d]; s_posnb[k*17+d] = p[d]; }
    float R[9];
    frame_from_pos(p, R);
    #pragma unroll
    for (int d = 0; d < 9; ++d) s_Rnb[k*13+d] = R[d];

    float pm = mask[n] * mask[nb] * ((nbraw != -1) ? 1.0f : 0.0f);
    out[N_RES*KNB*PCH + n*KNB + k] = pm;

    int rel = resi[nb] - resi[n];
    rel = (rel < -32) ? -32 : (rel > 32 ? 32 : rel);
    rel += 32;
    bool same = (chain[nb] == chain[n]) && (batch[nb] == batch[n]);
    s_cls[k] = same ? rel : 65;

    float xd = dmap[(long long)n*N_RES + nb] * INV_STEP;
    s_xall[k] = (pm > 0.0f) ? xd : 30.0f;     // 30 -> all bins underflow to 0
  } else if (t == 255) {
    float p[15];
    const float* pp = pos + n*15;
    #pragma unroll
    for (int d = 0; d < 15; ++d) { p[d] = pp[d]; s_posn[d] = p[d]; }
    float R[9];
    frame_from_pos(p, R);
    #pragma unroll
    for (int d = 0; d < 9; ++d) s_Rn[d] = R[d];
  }
  __syncthreads();

  // ---------------- P2: 25 atom-pair scaled distances ----------------
  for (int idx = t; idx < 1200; idx += 256) {
    int c = idx / 48, k = idx - 48*c;
    int a1 = c / 5, a2 = c - 5*a1;
    float dx = s_posn[a1*3+0] - s_posnb[k*17 + a2*3+0];
    float dy = s_posn[a1*3+1] - s_posnb[k*17 + a2*3+1];
    float dz = s_posn[a1*3+2] - s_posnb[k*17 + a2*3+2];
    float d2 = dx*dx + dy*dy + dz*dz;
    s_xall[48 + idx] = sqrtf(fmaxf(d2, 1e-12f)) * INV_STEP;
  }
  __syncthreads();

  // ---------------- GEMM1: 3x128-K stages + 96-K stage, software-pipelined ---
  f32x4 acc1[3][2] = {};
  const bool has1 = (t < 128);
  BinsReg br0, br1;

  // prologue: stage 0 bins -> regs -> LDS
  bins_compute(s_xall, 0, t, br0);
  if (has1) bins_compute(s_xall, 0, t+256, br1);
  bins_commit(sF, br0);
  if (has1) bins_commit(sF, br1);
  __syncthreads();

  uint4 dvreg;                 // dir/vec b128 (t<240)
  uint4 rot0, rot1;            // rot b128s (t>=208)

  #pragma unroll 1
  for (int st = 0; st < 3; ++st) {
    // ---- compute-early: stage st+1 data into regs (independent of sF) ----
    if (st < 2) {
      bins_compute(s_xall, (st+1)*8, t, br0);
      if (has1) bins_compute(s_xall, (st+1)*8, t+256, br1);
    } else {
      if (t < 96) bins_compute(s_xall, 24, t, br0);          // dist c23,c24
      if (t < 240) {                                         // dir+vec
        int k = t / 5, a = t - 5*k;
        float rx = s_posnb[k*17 + a*3+0] - s_posn[3];
        float ry = s_posnb[k*17 + a*3+1] - s_posn[4];
        float rz = s_posnb[k*17 + a*3+2] - s_posn[5];
        float l0 = s_Rn[0]*rx + s_Rn[3]*ry + s_Rn[6]*rz;
        float l1 = s_Rn[1]*rx + s_Rn[4]*ry + s_Rn[7]*rz;
        float l2 = s_Rn[2]*rx + s_Rn[5]*ry + s_Rn[8]*rz;
        float inv = __builtin_amdgcn_rsqf(fmaxf(l0*l0 + l1*l1 + l2*l2, 1e-6f));
        dvreg = make_uint4(pk2(l0*inv, l1*inv), pk2(l2*inv, l0), pk2(l1, l2), 0u);
      }
      if (t >= 208) {                                        // rot rows
        int k = t - 208;
        float rr[9];
        #pragma unroll
        for (int il = 0; il < 9; ++il) {
          int i2 = il / 3, l2c = il - 3*i2;
          rr[il] = s_Rn[0+i2]*s_Rnb[k*13 + 0+l2c]
                 + s_Rn[3+i2]*s_Rnb[k*13 + 3+l2c]
                 + s_Rn[6+i2]*s_Rnb[k*13 + 6+l2c];
        }
        rot0 = make_uint4(pk2(rr[0],rr[1]), pk2(rr[2],rr[3]),
                          pk2(rr[4],rr[5]), pk2(rr[6],rr[7]));
        rot1 = make_uint4(pk2(rr[8],0.0f), 0u, 0u, 0u);
      }
    }
    // ---- MFMA phase for stage st (interleaves with the compute above) ----
    #pragma unroll
    for (int kc = 0; kc < 4; ++kc) {
      const unsigned short* ab = sF + FOCT(kc*4 + quad, ln15);
      bf16x8 a0 = *(const bf16x8*)(ab);
      bf16x8 a1 = *(const bf16x8*)(ab + 128);
      bf16x8 a2 = *(const bf16x8*)(ab + 256);
      const unsigned short* bb = g_wcat + (((st*4+kc)*4 + quad)*128 + 32*wv + ln15)*8;
      bf16x8 b0 = *(const bf16x8*)(bb);
      bf16x8 b1v= *(const bf16x8*)(bb + 128);
      MFMA6(a0,a1,a2,b0,b1v,acc1)
    }
    __syncthreads();           // all reads of sF done
    // ---- store-late: commit stage st+1 to sF ----
    if (st < 2) {
      bins_commit(sF, br0);
      if (has1) bins_commit(sF, br1);
    } else {
      if (t < 96) bins_commit(sF, br0);
      if (t < 240) {
        int k = t / 5, a = t - 5*k;
        *(uint4*)(sF + FOCT(4+a, k)) = dvreg;
      }
      if (t >= 208) {
        int k = t - 208;
        *(uint4*)(sF + FOCT(9, k))  = rot0;
        *(uint4*)(sF + FOCT(10, k)) = rot1;
        *(uint4*)(sF + FOCT(11, k)) = make_uint4(0u, 0u, 0u, 0u);
      }
    }
    __syncthreads();
  }

  // stage 3 MFMA (3 kc: dist tail + dir/vec + rot)
  #pragma unroll
  for (int kc = 0; kc < 3; ++kc) {
    const unsigned short* ab = sF + FOCT(kc*4 + quad, ln15);
    bf16x8 a0 = *(const bf16x8*)(ab);
    bf16x8 a1 = *(const bf16x8*)(ab + 128);
    bf16x8 a2 = *(const bf16x8*)(ab + 256);
    const unsigned short* bb = g_wcat + (((12+kc)*4 + quad)*128 + 32*wv + ln15)*8;
    bf16x8 b0 = *(const bf16x8*)(bb);
    bf16x8 b1v= *(const bf16x8*)(bb + 128);
    MFMA6(a0,a1,a2,b0,b1v,acc1)
  }

  // ---------------- relpos: exact f32 table add (load at use) ----------------
  {
    int c0 = 32*wv + ln15;
    #pragma unroll
    for (int mt = 0; mt < 3; ++mt)
      #pragma unroll
      for (int r = 0; r < 4; ++r) {
        int row = mt*16 + quad*4 + r;
        const float* wr = W_relpos + s_cls[row]*128 + c0;
        acc1[mt][0][r] += wr[0];
        acc1[mt][1][r] += wr[16];
      }
  }

  // ---------------- LayerNorm in registers ----------------
  #pragma unroll
  for (int mt = 0; mt < 3; ++mt)
    #pragma unroll
    for (int r = 0; r < 4; ++r) {
      float a0v = acc1[mt][0][r], a1v = acc1[mt][1][r];
      float sv = a0v + a1v;
      float qv = a0v*a0v + a1v*a1v;
      #pragma unroll
      for (int msk = 1; msk < 16; msk <<= 1) {
        sv += __shfl_xor(sv, msk);
        qv += __shfl_xor(qv, msk);
      }
      if (ln15 == 0) s_part[wv*48 + mt*16 + quad*4 + r] = make_float2(sv, qv);
    }
  __syncthreads();
  if (t < 48) {
    float S = 0.0f, Q = 0.0f;
    #pragma unroll
    for (int w = 0; w < 4; ++w) { float2 p = s_part[w*48 + t]; S += p.x; Q += p.y; }
    float mu = S * (1.0f/128.0f);
    float var = Q * (1.0f/128.0f) - mu*mu;
    s_stats[t] = make_float2(mu, __builtin_amdgcn_rsqf(var + 1e-5f));
  }
  __syncthreads();
  {
    int c0 = 32*wv + ln15;
    f32x2 G; G[0] = ln_scale[c0];  G[1] = ln_scale[c0+16];
    f32x2 O; O[0] = ln_offset[c0]; O[1] = ln_offset[c0+16];
    int kp = 32*wv + 2*ln15;                 // sigma-permuted K position (even)
    int oct = kp >> 3, slot = kp & 7;
    #pragma unroll
    for (int mt = 0; mt < 3; ++mt)
      #pragma unroll
      for (int r = 0; r < 4; ++r) {
        int row = mt*16 + quad*4 + r;
        float2 stt = s_stats[row];
        f32x2 A; A[0] = acc1[mt][0][r]; A[1] = acc1[mt][1][r];
        f32x2 v = (A - stt.x) * stt.y;
        v = v*G + O;
        *(unsigned int*)(sPair + FOCT(oct,row) + slot) = pk2(v[0], v[1]);
      }
  }
  __syncthreads();

  // ---------------- MLP: both hidden halves in one pass ----------------
  // acc2a/acc2b from shared sPair A-frags (12 MFMA per kc); gelu half0 -> sF,
  // half1 -> sPair (dead after); then one 8-kc W2 GEMM. 2 barriers total.
  f32x4 acc2a[3][2] = {};
  f32x4 acc2b[3][2] = {};
  #pragma unroll
  for (int kc = 0; kc < 4; ++kc) {
    const unsigned short* ab = sPair + FOCT(kc*4 + quad, ln15);
    bf16x8 a0 = *(const bf16x8*)(ab);
    bf16x8 a1 = *(const bf16x8*)(ab + 128);
    bf16x8 a2 = *(const bf16x8*)(ab + 256);
    const unsigned short* bb = g_w1 + ((kc*4 + quad)*256 + 32*wv + ln15)*8;
    bf16x8 b0 = *(const bf16x8*)(bb);
    bf16x8 b1v= *(const bf16x8*)(bb + 128);
    bf16x8 b2v= *(const bf16x8*)(bb + 1024);   // +128 cols
    bf16x8 b3v= *(const bf16x8*)(bb + 1152);
    MFMA6(a0,a1,a2,b0,b1v,acc2a)
    MFMA6(a0,a1,a2,b2v,b3v,acc2b)
  }
  __syncthreads();   // all sPair reads done before overwrite
  {
    int hc = 32*wv + ln15;
    f32x2 B0; B0[0] = b1[hc];     B0[1] = b1[hc+16];
    f32x2 B1; B1[0] = b1[hc+128]; B1[1] = b1[hc+144];
    int kp = 32*wv + 2*ln15;
    int oct = kp >> 3, slot = kp & 7;
    #pragma unroll
    for (int mt = 0; mt < 3; ++mt)
      #pragma unroll
      for (int r = 0; r < 4; ++r) {
        int row = mt*16 + quad*4 + r;
        f32x2 Xa; Xa[0] = acc2a[mt][0][r]; Xa[1] = acc2a[mt][1][r];
        f32x2 Xb; Xb[0] = acc2b[mt][0][r]; Xb[1] = acc2b[mt][1][r];
        f32x2 ga = gelu2(Xa + B0);
        f32x2 gb = gelu2(Xb + B1);
        *(unsigned int*)(sF    + FOCT(oct,row) + slot) = pk2(ga[0], ga[1]);
        *(unsigned int*)(sPair + FOCT(oct,row) + slot) = pk2(gb[0], gb[1]);
      }
  }
  __syncthreads();
  f32x4 acc3[3][2] = {};
  #pragma unroll
  for (int kc2 = 0; kc2 < 8; ++kc2) {
    const unsigned short* src = (kc2 < 4) ? sF : sPair;
    const unsigned short* ab = src + FOCT((kc2 & 3)*4 + quad, ln15);
    bf16x8 a0 = *(const bf16x8*)(ab);
    bf16x8 a1 = *(const bf16x8*)(ab + 128);
    bf16x8 a2 = *(const bf16x8*)(ab + 256);
    const unsigned short* bb = g_w2 + ((kc2*4 + quad)*128 + 32*wv + ln15)*8;
    bf16x8 b0 = *(const bf16x8*)(bb);
    bf16x8 b1v= *(const bf16x8*)(bb + 128);
    MFMA6(a0,a1,a2,b0,b1v,acc3)
  }

  // ---------------- epilogue: out = acc3 + b2 ----------------
  {
    int c0 = 32*wv + ln15;
    float bo0 = b2[c0], bo1 = b2[c0+16];
    #pragma unroll
    for (int mt = 0; mt < 3; ++mt)
      #pragma unroll
      for (int r = 0; r < 4; ++r) {
        int row = mt*16 + quad*4 + r;
        out[(n*KNB + row)*PCH + c0]      = acc3[mt][0][r] + bo0;
        out[(n*KNB + row)*PCH + c0 + 16] = acc3[mt][1][r] + bo1;
      }
  }
}

extern "C" void kernel_launch(void* const* d_in, const int* in_sizes, int n_in,
                              void* d_out, int out_size, void* d_ws, size_t ws_size,
                              hipStream_t stream) {
  const float* pos       = (const float*)d_in[0];
  const float* dmap      = (const float*)d_in[1];
  const float* mask      = (const float*)d_in[2];
  const float* W_relpos  = (const float*)d_in[3];
  const float* W_dmap    = (const float*)d_in[4];
  const float* W_dist    = (const float*)d_in[5];
  const float* W_dir     = (const float*)d_in[6];
  const float* W_rot     = (const float*)d_in[7];
  const float* W_vec     = (const float*)d_in[8];
  const float* ln_scale  = (const float*)d_in[9];
  const float* ln_offset = (const float*)d_in[10];
  const float* W1        = (const float*)d_in[11];
  const float* b1        = (const float*)d_in[12];
  const float* W2        = (const float*)d_in[13];
  const float* b2        = (const float*)d_in[14];
  const int* neighbours  = (const int*)d_in[15];
  const int* resi        = (const int*)d_in[16];
  const int* chain       = (const int*)d_in[17];
  const int* batch       = (const int*)d_in[18];
  float* out = (float*)d_out;

  hipLaunchKernelGGL(prep_weights, dim3(62), dim3(256), 0, stream,
                     W_dmap, W_dist, W_dir, W_rot, W_vec, W1, W2);
  hipLaunchKernelGGL(fused_struct_kernel, dim3(N_RES), dim3(256), 0, stream,
                     pos, dmap, mask, W_relpos, ln_scale, ln_offset, b1, b2,
                     neighbours, resi, chain, batch, out);
}

// Round 8
// 264.178 us; speedup vs baseline: 1.2132x; 1.2132x over previous
//
#include <hip/hip_runtime.h>
#include <hip/hip_bf16.h>

// N=4096, K=48, P=128, A=5, NBINS=16, RP=32
#define N_RES 4096
#define KNB   48
#define PCH   128
#define INV_STEP 0.727272727272727f
#define E2C   7.38905609893065f       // e^2
#define EM2C  0.1353352832366127f     // e^-2
#define EM6C  2.4787521766663585e-3f  // e^-6
#define EM8C  3.3546262790251185e-4f  // e^-8

typedef __bf16 bf16x8 __attribute__((ext_vector_type(8)));
typedef float  f32x4  __attribute__((ext_vector_type(4)));
typedef float  f32x2  __attribute__((ext_vector_type(2)));   // lowers to v_pk_*_f32

// Frag-linear, PADDED layout: octet stride = 49 row-slots (16B each).
#define FOCT(o,m) (((o)*49 + (m))*8)

// wcat K-map (480 total, 60 octs):
//   0..15   dmap RBF            (octs 0..1)
//  16..415  dist RBF (25 pairs) (octs 2..51)
// 416..455  dir/vec per atom a: k=416+8a+[dx,dy,dz,vx,vy,vz,0,0] (octs 52..56)
// 456..464  rot (9)             (oct 57 + oct 58 slot 0)
// 465..479  zero                (rest of oct 58, oct 59)
__device__ __align__(16) unsigned short g_wcat[60*128*8];
// w1: K=128 (rows sigma-permuted: pairs (u,u+16) interleaved), 256 cols
__device__ __align__(16) unsigned short g_w1[16*256*8];
// w2: K=256 (rows sigma-permuted within each 128-half), 128 cols
__device__ __align__(16) unsigned short g_w2[32*128*8];

__device__ __forceinline__ unsigned short f2bf(float f) {
  unsigned int u = __float_as_uint(f);
  return (unsigned short)((u + 0x7fffu + ((u >> 16) & 1u)) >> 16);
}
__device__ __forceinline__ unsigned int pk2(float a, float b) {
  __hip_bfloat162 h = __float22bfloat162_rn(make_float2(a, b));
  unsigned int u; __builtin_memcpy(&u, &h, 4); return u;
}
// tanh-gelu == x * sigmoid(2u), u = 0.7978845608*(x + 0.044715 x^3); packed pair.
__device__ __forceinline__ f32x2 gelu2(f32x2 X) {
  f32x2 p = X*X;
  f32x2 q = p*0.044715f + 1.0f;
  f32x2 r = X*q;
  f32x2 m = r * -1.5957691216057308f;
  f32x2 E; E[0] = __expf(m[0]); E[1] = __expf(m[1]);
  f32x2 den = E + 1.0f;
  f32x2 sig; sig[0] = __builtin_amdgcn_rcpf(den[0]);
  sig[1] = __builtin_amdgcn_rcpf(den[1]);
  return X*sig;
}
__device__ __forceinline__ void frame_from_pos(const float* p, float* R) {
  float cax = p[3], cay = p[4], caz = p[5];
  float e1x = p[6]-cax, e1y = p[7]-cay, e1z = p[8]-caz;
  float i1 = __builtin_amdgcn_rsqf(fmaxf(e1x*e1x + e1y*e1y + e1z*e1z, 1e-6f));
  e1x *= i1; e1y *= i1; e1z *= i1;
  float vx = p[0]-cax, vy = p[1]-cay, vz = p[2]-caz;
  float dp = vx*e1x + vy*e1y + vz*e1z;
  float e2x = vx - dp*e1x, e2y = vy - dp*e1y, e2z = vz - dp*e1z;
  float i2 = __builtin_amdgcn_rsqf(fmaxf(e2x*e2x + e2y*e2y + e2z*e2z, 1e-6f));
  e2x *= i2; e2y *= i2; e2z *= i2;
  float e3x = e1y*e2z - e1z*e2y;
  float e3y = e1z*e2x - e1x*e2z;
  float e3z = e1x*e2y - e1y*e2x;
  R[0]=e1x; R[1]=e2x; R[2]=e3x;
  R[3]=e1y; R[4]=e2y; R[5]=e3y;
  R[6]=e1z; R[7]=e2z; R[8]=e3z;
}

// 16 RBF bins exp(-(x-b)^2) via PAIRED telescoping recurrences (up + down,
// merged with pk_max to dodge underflow). Pair step ratio multiplies by e^-8.
// x clamped to 23 so the pair ratios (<= e^88) and t^2 (= e^{4x-6} <= e^86)
// stay finite in f32; bins at x>=23 are < e^-64 ~= 0 regardless.
__device__ __forceinline__ void stage_bins(unsigned short* sF, const float* s_xall,
                                           int xbase, int ntasks, int t) {
  for (int i = t; i < ntasks; i += 256) {
    int rloc = i / 48;
    int m = i - 48*rloc;
    float x  = fminf(s_xall[(xbase + rloc)*48 + m], 23.0f);
    float u0 = __expf(-x*x);                 // bin 0
    float tt = __expf(2.0f*x - 3.0f);
    float xm = x - 15.0f;
    float d0 = __expf(-xm*xm);               // bin 15
    float ss = __expf(-2.0f*x + 29.0f);
    float t2 = tt*tt;                        // e^{4x-6}
    float s2 = ss*ss;                        // e^{-4x+58}
    f32x2 P;  P[0] = u0;       P[1] = u0*tt*E2C;        // (bin0, bin1)
    f32x2 W;  W[0] = t2*E2C;   W[1] = t2*EM2C;          // (e^{4x-4}, e^{4x-8})
    f32x2 Pn[8];
    Pn[0] = P;
    #pragma unroll
    for (int b = 1; b < 8; ++b) { P *= W; W *= EM8C; Pn[b] = P; }
    f32x2 q;  q[0] = d0*ss;    q[1] = d0;               // (bin14, bin15)
    f32x2 V;  V[0] = s2*EM6C;  V[1] = s2*EM2C;          // (e^{-4x+52}, e^{-4x+56})
    unsigned int pks[8];
    f32x2 o7 = __builtin_elementwise_max(Pn[7], q);
    pks[7] = pk2(o7[0], o7[1]);
    #pragma unroll
    for (int b = 6; b >= 0; --b) {
      q *= V; V *= EM8C;
      f32x2 o = __builtin_elementwise_max(Pn[b], q);
      pks[b] = pk2(o[0], o[1]);
    }
    int base = FOCT(2*rloc, m);
    *(uint4*)(sF + base)       = make_uint4(pks[0],pks[1],pks[2],pks[3]);
    *(uint4*)(sF + base + 392) = make_uint4(pks[4],pks[5],pks[6],pks[7]);
  }
}

// ---- prep: fragment-linear bf16 weights; wcat K-map per header comment;
// W1/W2 rows sigma-permuted to match paired (pk2/b32) LDS staging. ----
__global__ __launch_bounds__(256) void prep_weights(
    const float* __restrict__ W_dmap, const float* __restrict__ W_dist,
    const float* __restrict__ W_dir, const float* __restrict__ W_rot,
    const float* __restrict__ W_vec, const float* __restrict__ W1,
    const float* __restrict__ W2)
{
  int i = blockIdx.x*256 + threadIdx.x;
  unsigned short pk[8];
  if (i < 7680) {                       // wcat: oct = i>>7 (60), col = i&127
    int oct = i >> 7, col = i & 127;
    #pragma unroll
    for (int j = 0; j < 8; ++j) {
      int k = oct*8 + j;
      float v;
      if      (k < 16)  v = W_dmap[k*128 + col];
      else if (k < 416) v = W_dist[(k-16)*128 + col];
      else if (k < 456) {
        int a = (k-416) >> 3, jj = (k-416) & 7;
        v = (jj < 3) ? W_dir[(a*3+jj)*128 + col]
          : (jj < 6) ? W_vec[(a*3+jj-3)*128 + col] : 0.0f;
      }
      else if (k < 465) v = W_rot[(k-456)*128 + col];
      else              v = 0.0f;
      pk[j] = f2bf(v);
    }
    *(uint4*)(g_wcat + i*8) = *(uint4*)pk;
  } else if (i < 11776) {               // w1: oct(16) x col(256), rows permuted
    int j2 = i - 7680;
    int oct = j2 >> 8, col = j2 & 255;
    #pragma unroll
    for (int j = 0; j < 8; ++j) {
      int k = oct*8 + j;                // permuted row index
      int h = 32*(k>>5) + (k&1)*16 + ((k&31)>>1);   // original row
      pk[j] = f2bf(W1[h*256 + col]);
    }
    *(uint4*)(g_w1 + j2*8) = *(uint4*)pk;
  } else if (i < 15872) {               // w2: oct(32) x col(128), rows permuted per half
    int j3 = i - 11776;
    int oct = j3 >> 7, col = j3 & 127;
    #pragma unroll
    for (int j = 0; j < 8; ++j) {
      int k = oct*8 + j;                // permuted row 0..255
      int kh = k & 127;
      int h = (k>>7)*128 + 32*(kh>>5) + (kh&1)*16 + ((kh&31)>>1);
      pk[j] = f2bf(W2[h*128 + col]);
    }
    *(uint4*)(g_w2 + j3*8) = *(uint4*)pk;
  }
}

#define MFMA6(A0,A1,A2,B0,B1,ACC) \
  ACC[0][0] = __builtin_amdgcn_mfma_f32_16x16x32_bf16(A0, B0, ACC[0][0], 0,0,0); \
  ACC[1][0] = __builtin_amdgcn_mfma_f32_16x16x32_bf16(A1, B0, ACC[1][0], 0,0,0); \
  ACC[2][0] = __builtin_amdgcn_mfma_f32_16x16x32_bf16(A2, B0, ACC[2][0], 0,0,0); \
  ACC[0][1] = __builtin_amdgcn_mfma_f32_16x16x32_bf16(A0, B1, ACC[0][1], 0,0,0); \
  ACC[1][1] = __builtin_amdgcn_mfma_f32_16x16x32_bf16(A1, B1, ACC[1][1], 0,0,0); \
  ACC[2][1] = __builtin_amdgcn_mfma_f32_16x16x32_bf16(A2, B1, ACC[2][1], 0,0,0);

// ---- main: one block per residue, 256 threads; LDS 25600 B -> 6 blocks/CU ----
__global__ __launch_bounds__(256, 6) void fused_struct_kernel(
    const float* __restrict__ pos, const float* __restrict__ dmap,
    const float* __restrict__ mask, const float* __restrict__ W_relpos,
    const float* __restrict__ ln_scale, const float* __restrict__ ln_offset,
    const float* __restrict__ b1, const float* __restrict__ b2,
    const int* __restrict__ neighbours, const int* __restrict__ resi,
    const int* __restrict__ chain, const int* __restrict__ batch,
    float* __restrict__ out)
{
  const int n = blockIdx.x;
  const int t = threadIdx.x;
  const int lane = t & 63;
  const int wv   = t >> 6;
  const int ln15 = lane & 15;
  const int quad = lane >> 4;

  __shared__ __align__(16) char regF[12544];   // F stage / gelu half0 (padded frag-linear)
  __shared__ __align__(16) char regP[12672];   // scratch -> pairb -> gelu half1
  __shared__ __align__(16) float2 s_stats[48];

  unsigned short* sF    = (unsigned short*)regF;
  unsigned short* sPair = (unsigned short*)regP;
  // Conflict-free strides: 17 and 13 floats (gcd with 32 banks == 1).
  float*  s_posnb = (float*)regP;              // [48][17]  = 3264 B
  float*  s_Rnb   = (float*)(regP + 3264);     // [48][13]  = 2496 B
  float*  s_xall  = (float*)(regP + 5760);     // [26][48]  = 4992 B
  float*  s_posn  = (float*)(regP + 10752);    // 64 B
  float*  s_Rn    = (float*)(regP + 10816);    // 64 B
  int*    s_cls   = (int*)  (regP + 10880);    // 192 B
  float*  s_partS = (float*)(regP + 11072);    // [4][49] = 784 B
  float*  s_partQ = (float*)(regP + 11856);    // [4][49] = 784 B, ends 12640 <= 12672

  // ---------------- P1 ----------------
  if (t < KNB) {
    const int k = t;
    const int nbraw = neighbours[n*KNB + k];
    int nb = nbraw; if (nb < 0) nb += N_RES;
    float p[15];
    const float* pp = pos + nb*15;
    #pragma unroll
    for (int d = 0; d < 15; ++d) { p[d] = pp[d]; s_posnb[k*17+d] = p[d]; }
    float R[9];
    frame_from_pos(p, R);
    #pragma unroll
    for (int d = 0; d < 9; ++d) s_Rnb[k*13+d] = R[d];

    float pm = mask[n] * mask[nb] * ((nbraw != -1) ? 1.0f : 0.0f);
    out[N_RES*KNB*PCH + n*KNB + k] = pm;

    int rel = resi[nb] - resi[n];
    rel = (rel < -32) ? -32 : (rel > 32 ? 32 : rel);
    rel += 32;
    bool same = (chain[nb] == chain[n]) && (batch[nb] == batch[n]);
    s_cls[k] = same ? rel : 65;

    float xd = dmap[(long long)n*N_RES + nb] * INV_STEP;
    s_xall[k] = (pm > 0.0f) ? xd : 30.0f;     // 30 -> all bins underflow to 0
  } else if (t == 255) {
    float p[15];
    const float* pp = pos + n*15;
    #pragma unroll
    for (int d = 0; d < 15; ++d) { p[d] = pp[d]; s_posn[d] = p[d]; }
    float R[9];
    frame_from_pos(p, R);
    #pragma unroll
    for (int d = 0; d < 9; ++d) s_Rn[d] = R[d];
  }
  __syncthreads();

  // ---------------- P2: 25 atom-pair scaled distances ----------------
  for (int idx = t; idx < 1200; idx += 256) {
    int c = idx / 48, k = idx - 48*c;
    int a1 = c / 5, a2 = c - 5*a1;
    float dx = s_posn[a1*3+0] - s_posnb[k*17 + a2*3+0];
    float dy = s_posn[a1*3+1] - s_posnb[k*17 + a2*3+1];
    float dz = s_posn[a1*3+2] - s_posnb[k*17 + a2*3+2];
    float d2 = dx*dx + dy*dy + dz*dz;
    s_xall[48 + idx] = sqrtf(fmaxf(d2, 1e-12f)) * INV_STEP;
  }
  __syncthreads();

  // ---------------- GEMM1 over 3x128 + 1x96 K-stages ----------------
  f32x4 acc1[3][2] = {};

  #pragma unroll 1
  for (int st = 0; st < 3; ++st) {
    stage_bins(sF, s_xall, st*8, 384, t);
    __syncthreads();
    #pragma unroll
    for (int kc = 0; kc < 4; ++kc) {
      const unsigned short* ab = sF + FOCT(kc*4 + quad, ln15);
      bf16x8 a0 = *(const bf16x8*)(ab);
      bf16x8 a1 = *(const bf16x8*)(ab + 128);
      bf16x8 a2 = *(const bf16x8*)(ab + 256);
      const unsigned short* bb = g_wcat + (((st*4+kc)*4 + quad)*128 + 32*wv + ln15)*8;
      bf16x8 b0 = *(const bf16x8*)(bb);
      bf16x8 b1v= *(const bf16x8*)(bb + 128);
      MFMA6(a0,a1,a2,b0,b1v,acc1)
    }
    __syncthreads();
  }

  // stage 3: local octs 0..3 dist c23,c24 | 4..8 dir/vec per atom | 9..10 rot |
  //          11 zero. All stores are b128; all (oct,row) slots covered -> no
  //          separate zero-fill, single barrier.
  stage_bins(sF, s_xall, 24, 96, t);
  if (t < 240) {                               // dir+vec, one b128 per (k, atom)
    int k = t / 5, a = t - 5*k;
    float rx = s_posnb[k*17 + a*3+0] - s_posn[3];
    float ry = s_posnb[k*17 + a*3+1] - s_posn[4];
    float rz = s_posnb[k*17 + a*3+2] - s_posn[5];
    float l0 = s_Rn[0]*rx + s_Rn[3]*ry + s_Rn[6]*rz;
    float l1 = s_Rn[1]*rx + s_Rn[4]*ry + s_Rn[7]*rz;
    float l2 = s_Rn[2]*rx + s_Rn[5]*ry + s_Rn[8]*rz;
    float inv = __builtin_amdgcn_rsqf(fmaxf(l0*l0 + l1*l1 + l2*l2, 1e-6f));
    *(uint4*)(sF + FOCT(4+a, k)) =
        make_uint4(pk2(l0*inv, l1*inv), pk2(l2*inv, l0), pk2(l1, l2), 0u);
  }
  if (t >= 208) {                              // rot rows, 48 threads, 3 b128 each
    int k = t - 208;
    float rr[9];
    #pragma unroll
    for (int il = 0; il < 9; ++il) {
      int i2 = il / 3, l2c = il - 3*i2;
      rr[il] = s_Rn[0+i2]*s_Rnb[k*13 + 0+l2c]
             + s_Rn[3+i2]*s_Rnb[k*13 + 3+l2c]
             + s_Rn[6+i2]*s_Rnb[k*13 + 6+l2c];
    }
    *(uint4*)(sF + FOCT(9, k))  = make_uint4(pk2(rr[0],rr[1]), pk2(rr[2],rr[3]),
                                             pk2(rr[4],rr[5]), pk2(rr[6],rr[7]));
    *(uint4*)(sF + FOCT(10, k)) = make_uint4(pk2(rr[8],0.0f), 0u, 0u, 0u);
    *(uint4*)(sF + FOCT(11, k)) = make_uint4(0u, 0u, 0u, 0u);
  }
  __syncthreads();

  // relpos gathers issued BEFORE the stage-3 MFMA phase: no barrier between
  // issue and use, so no cross-barrier liveness (R2/R6 spill lesson); the
  // 18-MFMA phase below covers the L1/L2 hit latency.
  float rp0[12], rp1[12];
  {
    int c0 = 32*wv + ln15;
    #pragma unroll
    for (int mt = 0; mt < 3; ++mt)
      #pragma unroll
      for (int r = 0; r < 4; ++r) {
        int row = mt*16 + quad*4 + r;
        const float* wr = W_relpos + s_cls[row]*128 + c0;
        rp0[mt*4+r] = wr[0];
        rp1[mt*4+r] = wr[16];
      }
  }

  // stage 3 MFMA (3 kc: dist tail + dir/vec + rot)
  #pragma unroll
  for (int kc = 0; kc < 3; ++kc) {
    const unsigned short* ab = sF + FOCT(kc*4 + quad, ln15);
    bf16x8 a0 = *(const bf16x8*)(ab);
    bf16x8 a1 = *(const bf16x8*)(ab + 128);
    bf16x8 a2 = *(const bf16x8*)(ab + 256);
    const unsigned short* bb = g_wcat + (((12+kc)*4 + quad)*128 + 32*wv + ln15)*8;
    bf16x8 b0 = *(const bf16x8*)(bb);
    bf16x8 b1v= *(const bf16x8*)(bb + 128);
    MFMA6(a0,a1,a2,b0,b1v,acc1)
  }

  // ---------------- relpos: exact f32 table add ----------------
  #pragma unroll
  for (int mt = 0; mt < 3; ++mt)
    #pragma unroll
    for (int r = 0; r < 4; ++r) {
      acc1[mt][0][r] += rp0[mt*4+r];
      acc1[mt][1][r] += rp1[mt*4+r];
    }

  // ---------------- LayerNorm in registers ----------------
  #pragma unroll
  for (int mt = 0; mt < 3; ++mt)
    #pragma unroll
    for (int r = 0; r < 4; ++r) {
      float a0v = acc1[mt][0][r], a1v = acc1[mt][1][r];
      float sv = a0v + a1v;
      float qv = a0v*a0v + a1v*a1v;
      #pragma unroll
      for (int msk = 1; msk < 16; msk <<= 1) {
        sv += __shfl_xor(sv, msk);
        qv += __shfl_xor(qv, msk);
      }
      if (ln15 == 0) {
        int row = mt*16 + quad*4 + r;
        s_partS[wv*49 + row] = sv;
        s_partQ[wv*49 + row] = qv;
      }
    }
  __syncthreads();
  if (t < 48) {
    float S = 0.0f, Q = 0.0f;
    #pragma unroll
    for (int w = 0; w < 4; ++w) { S += s_partS[w*49 + t]; Q += s_partQ[w*49 + t]; }
    float mu = S * (1.0f/128.0f);
    float var = Q * (1.0f/128.0f) - mu*mu;
    s_stats[t] = make_float2(mu, __builtin_amdgcn_rsqf(var + 1e-5f));
  }
  __syncthreads();
  {
    int c0 = 32*wv + ln15;
    f32x2 G; G[0] = ln_scale[c0];  G[1] = ln_scale[c0+16];
    f32x2 O; O[0] = ln_offset[c0]; O[1] = ln_offset[c0+16];
    int kp = 32*wv + 2*ln15;                 // sigma-permuted K position (even)
    int oct = kp >> 3, slot = kp & 7;
    #pragma unroll
    for (int mt = 0; mt < 3; ++mt)
      #pragma unroll
      for (int r = 0; r < 4; ++r) {
        int row = mt*16 + quad*4 + r;
        float2 stt = s_stats[row];
        f32x2 A; A[0] = acc1[mt][0][r]; A[1] = acc1[mt][1][r];
        f32x2 v = (A - stt.x) * stt.y;
        v = v*G + O;
        *(unsigned int*)(sPair + FOCT(oct,row) + slot) = pk2(v[0], v[1]);
      }
  }
  __syncthreads();

  // ---------------- MLP: both hidden halves in one pass ----------------
  // acc2a/acc2b from shared sPair A-frags (12 MFMA per kc); gelu half0 -> sF,
  // half1 -> sPair (dead after); then one 8-kc W2 GEMM. 2 barriers total.
  f32x4 acc2a[3][2] = {};
  f32x4 acc2b[3][2] = {};
  #pragma unroll
  for (int kc = 0; kc < 4; ++kc) {
    const unsigned short* ab = sPair + FOCT(kc*4 + quad, ln15);
    bf16x8 a0 = *(const bf16x8*)(ab);
    bf16x8 a1 = *(const bf16x8*)(ab + 128);
    bf16x8 a2 = *(const bf16x8*)(ab + 256);
    const unsigned short* bb = g_w1 + ((kc*4 + quad)*256 + 32*wv + ln15)*8;
    bf16x8 b0 = *(const bf16x8*)(bb);
    bf16x8 b1v= *(const bf16x8*)(bb + 128);
    bf16x8 b2v= *(const bf16x8*)(bb + 1024);   // +128 cols
    bf16x8 b3v= *(const bf16x8*)(bb + 1152);
    MFMA6(a0,a1,a2,b0,b1v,acc2a)
    MFMA6(a0,a1,a2,b2v,b3v,acc2b)
  }
  __syncthreads();   // all sPair reads done before overwrite
  {
    int hc = 32*wv + ln15;
    f32x2 B0; B0[0] = b1[hc];     B0[1] = b1[hc+16];
    f32x2 B1; B1[0] = b1[hc+128]; B1[1] = b1[hc+144];
    int kp = 32*wv + 2*ln15;
    int oct = kp >> 3, slot = kp & 7;
    #pragma unroll
    for (int mt = 0; mt < 3; ++mt)
      #pragma unroll
      for (int r = 0; r < 4; ++r) {
        int row = mt*16 + quad*4 + r;
        f32x2 Xa; Xa[0] = acc2a[mt][0][r]; Xa[1] = acc2a[mt][1][r];
        f32x2 Xb; Xb[0] = acc2b[mt][0][r]; Xb[1] = acc2b[mt][1][r];
        f32x2 ga = gelu2(Xa + B0);
        f32x2 gb = gelu2(Xb + B1);
        *(unsigned int*)(sF    + FOCT(oct,row) + slot) = pk2(ga[0], ga[1]);
        *(unsigned int*)(sPair + FOCT(oct,row) + slot) = pk2(gb[0], gb[1]);
      }
  }
  __syncthreads();
  f32x4 acc3[3][2] = {};
  #pragma unroll
  for (int kc2 = 0; kc2 < 8; ++kc2) {
    const unsigned short* src = (kc2 < 4) ? sF : sPair;
    const unsigned short* ab = src + FOCT((kc2 & 3)*4 + quad, ln15);
    bf16x8 a0 = *(const bf16x8*)(ab);
    bf16x8 a1 = *(const bf16x8*)(ab + 128);
    bf16x8 a2 = *(const bf16x8*)(ab + 256);
    const unsigned short* bb = g_w2 + ((kc2*4 + quad)*128 + 32*wv + ln15)*8;
    bf16x8 b0 = *(const bf16x8*)(bb);
    bf16x8 b1v= *(const bf16x8*)(bb + 128);
    MFMA6(a0,a1,a2,b0,b1v,acc3)
  }

  // ---------------- epilogue: out = acc3 + b2 ----------------
  {
    int c0 = 32*wv + ln15;
    float bo0 = b2[c0], bo1 = b2[c0+16];
    #pragma unroll
    for (int mt = 0; mt < 3; ++mt)
      #pragma unroll
      for (int r = 0; r < 4; ++r) {
        int row = mt*16 + quad*4 + r;
        out[(n*KNB + row)*PCH + c0]      = acc3[mt][0][r] + bo0;
        out[(n*KNB + row)*PCH + c0 + 16] = acc3[mt][1][r] + bo1;
      }
  }
}

extern "C" void kernel_launch(void* const* d_in, const int* in_sizes, int n_in,
                              void* d_out, int out_size, void* d_ws, size_t ws_size,
                              hipStream_t stream) {
  const float* pos       = (const float*)d_in[0];
  const float* dmap      = (const float*)d_in[1];
  const float* mask      = (const float*)d_in[2];
  const float* W_relpos  = (const float*)d_in[3];
  const float* W_dmap    = (const float*)d_in[4];
  const float* W_dist    = (const float*)d_in[5];
  const float* W_dir     = (const float*)d_in[6];
  const float* W_rot     = (const float*)d_in[7];
  const float* W_vec     = (const float*)d_in[8];
  const float* ln_scale  = (const float*)d_in[9];
  const float* ln_offset = (const float*)d_in[10];
  const float* W1        = (const float*)d_in[11];
  const float* b1        = (const float*)d_in[12];
  const float* W2        = (const float*)d_in[13];
  const float* b2        = (const float*)d_in[14];
  const int* neighbours  = (const int*)d_in[15];
  const int* resi        = (const int*)d_in[16];
  const int* chain       = (const int*)d_in[17];
  const int* batch       = (const int*)d_in[18];
  float* out = (float*)d_out;

  hipLaunchKernelGGL(prep_weights, dim3(62), dim3(256), 0, stream,
                     W_dmap, W_dist, W_dir, W_rot, W_vec, W1, W2);
  hipLaunchKernelGGL(fused_struct_kernel, dim3(N_RES), dim3(256), 0, stream,
                     pos, dmap, mask, W_relpos, ln_scale, ln_offset, b1, b2,
                     neighbours, resi, chain, batch, out);
}